// Round 1
// baseline (422.920 us; speedup 1.0000x reference)
//
#include <hip/hip_runtime.h>
#include <math.h>

// Problem constants (match reference: X[2, 8192, 64] f32, K=10)
#define B_    2
#define N_    8192
#define D_    64
#define K_    10
#define NC_   8                 // candidate-axis chunks per point
#define CHUNK_ (N_ / NC_)       // 1024 candidates per chunk
#define TILE_M 128              // candidate rows staged in LDS per stage (32 KB)
#define INF_  3.4e38f

// ---------------------------------------------------------------------------
// Kernel 1: squared norms per point
// ---------------------------------------------------------------------------
__global__ __launch_bounds__(256) void norms_kernel(const float* __restrict__ X,
                                                    float* __restrict__ norms) {
    const int p = blockIdx.x * 256 + threadIdx.x;      // 0 .. B*N-1
    const float4* x4 = (const float4*)(X + (size_t)p * D_);
    float acc = 0.f;
#pragma unroll
    for (int i = 0; i < D_ / 4; ++i) {
        float4 v = x4[i];
        acc = fmaf(v.x, v.x, acc);
        acc = fmaf(v.y, v.y, acc);
        acc = fmaf(v.z, v.z, acc);
        acc = fmaf(v.w, v.w, acc);
    }
    norms[p] = acc;
}

// ---------------------------------------------------------------------------
// Kernel 2: per (point, chunk) partial top-10 smallest squared distances,
// self excluded. One thread per point; candidate tile staged in LDS and
// read as wave-uniform broadcasts.
// ---------------------------------------------------------------------------
__global__ __launch_bounds__(256, 2) void knn_chunk_kernel(const float* __restrict__ X,
                                                           const float* __restrict__ norms,
                                                           float* __restrict__ part) {
    __shared__ float smem[TILE_M * D_];   // 32 KB candidate tile
    __shared__ float snorm[TILE_M];

    const int tid   = threadIdx.x;
    const int chunk = blockIdx.x;         // 0..NC_-1
    const int b     = blockIdx.z;         // batch
    const int n     = blockIdx.y * 256 + tid;
    const int pn    = b * N_ + n;

    // x_n into registers (64 VGPRs)
    float4 xn[D_ / 4];
    {
        const float4* xsrc = (const float4*)(X + (size_t)pn * D_);
#pragma unroll
        for (int i = 0; i < D_ / 4; ++i) xn[i] = xsrc[i];
    }
    const float sqn = norms[pn];

    // sorted ascending top-10 of squared distances
    float t[K_];
#pragma unroll
    for (int j = 0; j < K_; ++j) t[j] = INF_;

    for (int s = 0; s < CHUNK_ / TILE_M; ++s) {
        const int m0 = chunk * CHUNK_ + s * TILE_M;
        __syncthreads();
        // stage TILE_M candidate rows (contiguous 32 KB) coalesced as float4
        {
            const float4* src = (const float4*)(X + ((size_t)b * N_ + m0) * D_);
            float4* dst = (float4*)smem;
#pragma unroll
            for (int i = 0; i < (TILE_M * D_ / 4) / 256; ++i)  // 8 iters
                dst[tid + i * 256] = src[tid + i * 256];
            if (tid < TILE_M) snorm[tid] = norms[b * N_ + m0 + tid];
        }
        __syncthreads();

        for (int mm = 0; mm < TILE_M; ++mm) {
            const float4* xm = (const float4*)(smem + mm * D_);
            float a0 = 0.f, a1 = 0.f, a2 = 0.f, a3 = 0.f;
#pragma unroll
            for (int i = 0; i < D_ / 4; ++i) {
                float4 v = xm[i];           // wave-uniform LDS broadcast
                a0 = fmaf(v.x, xn[i].x, a0);
                a1 = fmaf(v.y, xn[i].y, a1);
                a2 = fmaf(v.z, xn[i].z, a2);
                a3 = fmaf(v.w, xn[i].w, a3);
            }
            const float dot = (a0 + a1) + (a2 + a3);
            float q = sqn + snorm[mm] - 2.f * dot;
            if (m0 + mm == n) q = INF_;     // exclude self
            if (q < t[K_ - 1]) {
                t[K_ - 1] = q;              // replace max, one bubble pass
#pragma unroll
                for (int j = K_ - 1; j > 0; --j) {
                    const float lo = fminf(t[j - 1], t[j]);
                    const float hi = fmaxf(t[j - 1], t[j]);
                    t[j - 1] = lo;
                    t[j]     = hi;
                }
            }
        }
    }

    float* o = part + ((size_t)pn * NC_ + chunk) * K_;
#pragma unroll
    for (int j = 0; j < K_; ++j) o[j] = t[j];
}

// ---------------------------------------------------------------------------
// Kernel 3: merge NC_ partial lists per point, compute S_n, block-reduce.
// S_n = 0.5 * (9*log q9 - sum_{j<9} log qj), q = clamped squared distance.
// ---------------------------------------------------------------------------
__global__ __launch_bounds__(256) void merge_kernel(const float* __restrict__ part,
                                                    float* __restrict__ bsum) {
    __shared__ float red[256];
    const int tid = threadIdx.x;
    const int p   = blockIdx.x * 256 + tid;   // 0 .. B*N-1
    const float* src = part + (size_t)p * NC_ * K_;

    float t[K_];
#pragma unroll
    for (int j = 0; j < K_; ++j) t[j] = INF_;
    for (int i = 0; i < NC_ * K_; ++i) {
        const float q = src[i];
        if (q < t[K_ - 1]) {
            t[K_ - 1] = q;
#pragma unroll
            for (int j = K_ - 1; j > 0; --j) {
                const float lo = fminf(t[j - 1], t[j]);
                const float hi = fmaxf(t[j - 1], t[j]);
                t[j - 1] = lo;
                t[j]     = hi;
            }
        }
    }

    const float q9 = fmaxf(t[K_ - 1], 1e-12f);
    float S = 9.f * logf(q9);
#pragma unroll
    for (int j = 0; j < K_ - 1; ++j) S -= logf(fmaxf(t[j], 1e-12f));
    S *= 0.5f;

    red[tid] = S;
    __syncthreads();
    for (int off = 128; off > 0; off >>= 1) {
        if (tid < off) red[tid] += red[tid + off];
        __syncthreads();
    }
    if (tid == 0) bsum[blockIdx.x] = red[0];
}

// ---------------------------------------------------------------------------
// Kernel 4: final reduction -> dim[b] = 9*N / sum_n S_n
// (block-partials 0..31 are batch 0, 32..63 batch 1)
// ---------------------------------------------------------------------------
__global__ void final_kernel(const float* __restrict__ bsum, float* __restrict__ out) {
    if (threadIdx.x == 0) {
        for (int b = 0; b < B_; ++b) {
            float s = 0.f;
            for (int i = 0; i < N_ / 256; ++i) s += bsum[b * (N_ / 256) + i];
            out[b] = 9.f * (float)N_ / s;
        }
    }
}

// ---------------------------------------------------------------------------
extern "C" void kernel_launch(void* const* d_in, const int* in_sizes, int n_in,
                              void* d_out, int out_size, void* d_ws, size_t ws_size,
                              hipStream_t stream) {
    const float* X = (const float*)d_in[0];
    float* out = (float*)d_out;
    float* ws  = (float*)d_ws;

    // ws layout (floats): norms[B*N] | part[B*N*NC*K] | bsum[B*N/256]
    float* norms = ws;
    float* part  = norms + (size_t)B_ * N_;
    float* bsum  = part + (size_t)B_ * N_ * NC_ * K_;

    norms_kernel<<<(B_ * N_) / 256, 256, 0, stream>>>(X, norms);

    dim3 grid(NC_, N_ / 256, B_);
    knn_chunk_kernel<<<grid, 256, 0, stream>>>(X, norms, part);

    merge_kernel<<<(B_ * N_) / 256, 256, 0, stream>>>(part, bsum);

    final_kernel<<<1, 64, 0, stream>>>(bsum, out);
}

// Round 2
// 249.765 us; speedup vs baseline: 1.6933x; 1.6933x over previous
//
#include <hip/hip_runtime.h>
#include <math.h>
#include <stdint.h>

#define B_ 2
#define N_ 8192
#define D_ 64
#define K_ 10
#define TILE_M 128              // candidates per chunk
#define NCHUNK (N_ / TILE_M)    // 64
#define ROWS_PB 64              // rows (n) per block
#define INF_ 3.4e38f

typedef __attribute__((ext_vector_type(8))) short bf16x8;
typedef __attribute__((ext_vector_type(4))) float f32x4;

// ---------------------------------------------------------------------------
// Prep: f32 -> bf16 (RNE) with XOR slot-swizzle baked into the global layout,
// plus bf16-consistent squared norms. Thread = (point, 8-dim slot).
// Layout: Xsw[point][slot^(point&7)][8 bf16]; row stride 64 halves (128 B).
// ---------------------------------------------------------------------------
__global__ __launch_bounds__(256) void prep_kernel(const float* __restrict__ X,
                                                   uint16_t* __restrict__ Xsw,
                                                   float* __restrict__ norms) {
    const int id = blockIdx.x * 256 + threadIdx.x;   // 0 .. B*N*8-1
    const int p = id >> 3;                           // global point
    const int slot = id & 7;
    const float4* s4 = (const float4*)(X + (size_t)p * D_ + slot * 8);
    float4 va = s4[0], vb = s4[1];
    float v[8] = {va.x, va.y, va.z, va.w, vb.x, vb.y, vb.z, vb.w};
    uint32_t h[8];
    float ss = 0.f;
#pragma unroll
    for (int i = 0; i < 8; ++i) {
        uint32_t u = __float_as_uint(v[i]);
        uint32_t r = (u + 0x7FFFu + ((u >> 16) & 1u)) & 0xFFFF0000u;  // RNE
        h[i] = r >> 16;
        float rv = __uint_as_float(r);
        ss = fmaf(rv, rv, ss);
    }
    uint4 w;
    w.x = h[0] | (h[1] << 16);
    w.y = h[2] | (h[3] << 16);
    w.z = h[4] | (h[5] << 16);
    w.w = h[6] | (h[7] << 16);
    *(uint4*)(Xsw + (size_t)p * D_ + (size_t)((slot ^ (p & 7)) * 8)) = w;
    // 8 slot-threads of one point are consecutive lanes: butterfly-sum
    ss += __shfl_xor(ss, 1);
    ss += __shfl_xor(ss, 2);
    ss += __shfl_xor(ss, 4);
    if (slot == 0) norms[p] = ss;
}

// ---------------------------------------------------------------------------
__device__ __forceinline__ void ins10(float (&t)[K_], float q) {
    if (q < t[K_ - 1]) {
        t[K_ - 1] = q;
#pragma unroll
        for (int j = K_ - 1; j > 0; --j) {
            const float lo = fminf(t[j - 1], t[j]);
            const float hi = fmaxf(t[j - 1], t[j]);
            t[j - 1] = lo;
            t[j] = hi;
        }
    }
}

// One 128-candidate chunk: 8 m-subtiles x (K=64 via 2 mfma). A = candidates
// (rows of C), B = this wave's 16 points n (cols of C). C layout (verified):
// col = lane&15 (our n), row = (lane>>4)*4 + reg (candidate).
template <bool SELF>
__device__ __forceinline__ void compute_chunk(const unsigned short* __restrict__ tile,
                                              const float* __restrict__ sn,
                                              const bf16x8 bfrag[2],
                                              float sqn, float (&t)[K_],
                                              int mbase, int n_my, int c15, int g4) {
#pragma unroll
    for (int ms = 0; ms < 8; ++ms) {
        const int p_loc = ms * 16 + c15;             // A-fragment row = lane&15
        f32x4 acc = {0.f, 0.f, 0.f, 0.f};
        const int slot0 = (g4) ^ (p_loc & 7);
        const int slot1 = (4 + g4) ^ (p_loc & 7);
        bf16x8 a0 = *(const bf16x8*)(tile + p_loc * 64 + slot0 * 8);
        bf16x8 a1 = *(const bf16x8*)(tile + p_loc * 64 + slot1 * 8);
        acc = __builtin_amdgcn_mfma_f32_16x16x32_bf16(a0, bfrag[0], acc, 0, 0, 0);
        acc = __builtin_amdgcn_mfma_f32_16x16x32_bf16(a1, bfrag[1], acc, 0, 0, 0);

        const f32x4 sq4 = *(const f32x4*)(sn + ms * 16 + g4 * 4);
        float q0 = fmaf(-2.f, acc[0], sqn + sq4[0]);
        float q1 = fmaf(-2.f, acc[1], sqn + sq4[1]);
        float q2 = fmaf(-2.f, acc[2], sqn + sq4[2]);
        float q3 = fmaf(-2.f, acc[3], sqn + sq4[3]);
        if (SELF) {
            const int mg = mbase + ms * 16 + g4 * 4;  // C-row -> candidate id
            if (mg + 0 == n_my) q0 = INF_;
            if (mg + 1 == n_my) q1 = INF_;
            if (mg + 2 == n_my) q2 = INF_;
            if (mg + 3 == n_my) q3 = INF_;
        }
        const float qm = fminf(fminf(q0, q1), fminf(q2, q3));
        if (qm < t[K_ - 1]) {
            ins10(t, q0);
            ins10(t, q1);
            ins10(t, q2);
            ins10(t, q3);
        }
    }
}

// ---------------------------------------------------------------------------
// Main: block = 4 waves x 16 rows = 64 rows, sweeps all 8192 candidates.
// Double-buffered reg-staged candidate tiles (issue-early / write-late).
// Ends with 4-lane list merge + S_n = 0.5*(9 log q9 - sum log qj), block sum.
// ---------------------------------------------------------------------------
__global__ __launch_bounds__(256, 1) void knn_main_kernel(const uint16_t* __restrict__ Xsw,
                                                          const float* __restrict__ norms,
                                                          float* __restrict__ bsum) {
    __shared__ __align__(16) unsigned short tile[2][TILE_M * 64];  // 2 x 16 KB
    __shared__ __align__(16) float sn[2][TILE_M];
    __shared__ __align__(16) float mb[4 * 64 * K_];                // 10 KB
    __shared__ float sred[ROWS_PB];

    const int tid = threadIdx.x;
    const int lane = tid & 63;
    const int wid = tid >> 6;
    const int blk = blockIdx.x;      // 0..255
    const int b = blk >> 7;
    const int nbase = (blk & 127) * ROWS_PB;
    const int c15 = lane & 15;
    const int g4 = lane >> 4;

    // B-fragments: this wave's 16 rows, 2 K-steps, from swizzled global layout
    const int n_my = nbase + wid * 16 + c15;
    bf16x8 bfrag[2];
    {
        const uint16_t* row = Xsw + ((size_t)(b * N_ + n_my)) * 64;
#pragma unroll
        for (int ks = 0; ks < 2; ++ks) {
            const int slot = (ks * 4 + g4) ^ (n_my & 7);
            bfrag[ks] = *(const bf16x8*)(row + slot * 8);
        }
    }
    const float sqn = norms[b * N_ + n_my];

    float t[K_];
#pragma unroll
    for (int j = 0; j < K_; ++j) t[j] = INF_;

    const int selfchunk = nbase >> 7;

    // prologue: stage chunk 0
    {
        const uint4* src = (const uint4*)(Xsw + (size_t)(b * N_) * 64);
        uint4* dst = (uint4*)&tile[0][0];
#pragma unroll
        for (int i = 0; i < 4; ++i) dst[tid + i * 256] = src[tid + i * 256];
        if (tid < TILE_M) sn[0][tid] = norms[b * N_ + tid];
    }
    __syncthreads();

    for (int ch = 0; ch < NCHUNK; ++ch) {
        const int cur = ch & 1;
        uint4 st[4];
        float stn = 0.f;
        const bool more = (ch + 1 < NCHUNK);
        if (more) {  // issue next-tile global loads early (hide under compute)
            const uint4* src =
                (const uint4*)(Xsw + ((size_t)(b * N_) + (size_t)(ch + 1) * TILE_M) * 64);
#pragma unroll
            for (int i = 0; i < 4; ++i) st[i] = src[tid + i * 256];
            if (tid < TILE_M) stn = norms[b * N_ + (ch + 1) * TILE_M + tid];
        }

        if (ch == selfchunk)
            compute_chunk<true>(&tile[cur][0], &sn[cur][0], bfrag, sqn, t,
                                ch * TILE_M, n_my, c15, g4);
        else
            compute_chunk<false>(&tile[cur][0], &sn[cur][0], bfrag, sqn, t,
                                 ch * TILE_M, n_my, c15, g4);

        if (more) {  // write-late into the other buffer
            uint4* dst = (uint4*)&tile[cur ^ 1][0];
#pragma unroll
            for (int i = 0; i < 4; ++i) dst[tid + i * 256] = st[i];
            if (tid < TILE_M) sn[cur ^ 1][tid] = stn;
        }
        __syncthreads();
    }

    // dump per-lane lists
    {
        float* my = &mb[(wid * 64 + lane) * K_];
#pragma unroll
        for (int j = 0; j < K_; ++j) my[j] = t[j];
    }
    __syncthreads();

    // per-row merge of the 4 lane-group lists + Levina-Bickel partial sum
    if (tid < ROWS_PB) {
        const int w = tid >> 4, c = tid & 15;
        float o[K_];
#pragma unroll
        for (int j = 0; j < K_; ++j) o[j] = INF_;
        for (int g = 0; g < 4; ++g) {
            const float* src = &mb[(w * 64 + g * 16 + c) * K_];
#pragma unroll
            for (int j = 0; j < K_; ++j) ins10(o, src[j]);
        }
        const float q9 = fmaxf(o[K_ - 1], 1e-12f);
        float S = 9.f * logf(q9);
#pragma unroll
        for (int j = 0; j < K_ - 1; ++j) S -= logf(fmaxf(o[j], 1e-12f));
        sred[tid] = 0.5f * S;
    }
    __syncthreads();
    if (tid == 0) {
        float s = 0.f;
        for (int i = 0; i < ROWS_PB; ++i) s += sred[i];
        bsum[blk] = s;
    }
}

// ---------------------------------------------------------------------------
__global__ void final_kernel(const float* __restrict__ bsum, float* __restrict__ out) {
    if (threadIdx.x == 0) {
        for (int b = 0; b < B_; ++b) {
            float s = 0.f;
            for (int i = 0; i < N_ / ROWS_PB; ++i) s += bsum[b * (N_ / ROWS_PB) + i];
            out[b] = 9.f * (float)N_ / s;
        }
    }
}

// ---------------------------------------------------------------------------
extern "C" void kernel_launch(void* const* d_in, const int* in_sizes, int n_in,
                              void* d_out, int out_size, void* d_ws, size_t ws_size,
                              hipStream_t stream) {
    const float* X = (const float*)d_in[0];
    float* out = (float*)d_out;

    // ws: Xsw (2 MB bf16 swizzled) | norms (64 KB) | bsum (1 KB)
    uint16_t* Xsw = (uint16_t*)d_ws;
    float* norms = (float*)((char*)d_ws + (size_t)B_ * N_ * D_ * sizeof(uint16_t));
    float* bsum = norms + (size_t)B_ * N_;

    prep_kernel<<<(B_ * N_ * 8) / 256, 256, 0, stream>>>(X, Xsw, norms);
    knn_main_kernel<<<B_ * (N_ / ROWS_PB), 256, 0, stream>>>(Xsw, norms, bsum);
    final_kernel<<<1, 64, 0, stream>>>(bsum, out);
}

// Round 3
// 133.315 us; speedup vs baseline: 3.1723x; 1.8735x over previous
//
#include <hip/hip_runtime.h>
#include <math.h>
#include <stdint.h>

#define B_ 2
#define N_ 8192
#define D_ 64
#define K_ 10
#define TILE_M 128               // candidates per chunk
#define CSPLIT 4                 // candidate-axis split (blocks per row-group)
#define CAND_PB (N_ / CSPLIT)    // 2048 candidates per block
#define NCH (CAND_PB / TILE_M)   // 16 chunks per block
#define ROWS_PB 64               // rows per block (4 waves x 16)
#define C_ 16                    // per-lane survivor-stack capacity
#define INF_ 3.4e38f

typedef __attribute__((ext_vector_type(8))) short bf16x8;
typedef __attribute__((ext_vector_type(4))) float f32x4;

// ---------------------------------------------------------------------------
// Prep: f32 -> bf16 (RNE) with XOR slot-swizzle baked into the global layout,
// plus bf16-consistent squared norms. Thread = (point, 8-dim slot).
// Layout: Xsw[point][slot^(point&7)][8 bf16]; row stride 64 halves (128 B).
// ---------------------------------------------------------------------------
__global__ __launch_bounds__(256) void prep_kernel(const float* __restrict__ X,
                                                   uint16_t* __restrict__ Xsw,
                                                   float* __restrict__ norms) {
    const int id = blockIdx.x * 256 + threadIdx.x;   // 0 .. B*N*8-1
    const int p = id >> 3;                           // global point
    const int slot = id & 7;
    const float4* s4 = (const float4*)(X + (size_t)p * D_ + slot * 8);
    float4 va = s4[0], vb = s4[1];
    float v[8] = {va.x, va.y, va.z, va.w, vb.x, vb.y, vb.z, vb.w};
    uint32_t h[8];
    float ss = 0.f;
#pragma unroll
    for (int i = 0; i < 8; ++i) {
        uint32_t u = __float_as_uint(v[i]);
        uint32_t r = (u + 0x7FFFu + ((u >> 16) & 1u)) & 0xFFFF0000u;  // RNE
        h[i] = r >> 16;
        float rv = __uint_as_float(r);
        ss = fmaf(rv, rv, ss);
    }
    uint4 w;
    w.x = h[0] | (h[1] << 16);
    w.y = h[2] | (h[3] << 16);
    w.z = h[4] | (h[5] << 16);
    w.w = h[6] | (h[7] << 16);
    *(uint4*)(Xsw + (size_t)p * D_ + (size_t)((slot ^ (p & 7)) * 8)) = w;
    ss += __shfl_xor(ss, 1);
    ss += __shfl_xor(ss, 2);
    ss += __shfl_xor(ss, 4);
    if (slot == 0) norms[p] = ss;
}

// ---------------------------------------------------------------------------
__device__ __forceinline__ void ins10(float (&t)[K_], float q) {
    if (q < t[K_ - 1]) {
        t[K_ - 1] = q;
#pragma unroll
        for (int j = K_ - 1; j > 0; --j) {
            const float lo = fminf(t[j - 1], t[j]);
            const float hi = fmaxf(t[j - 1], t[j]);
            t[j - 1] = lo;
            t[j] = hi;
        }
    }
}

// Drain this lane's survivor stack into its sorted top-10; refresh tau.
__device__ __forceinline__ void compact(float (&t)[K_], float& tau, int& cnt,
                                        const float* __restrict__ stackm, int tid) {
#pragma unroll
    for (int s = 0; s < C_; ++s) {
        const float q = stackm[s * 256 + tid];   // conflict-free: bank = tid%32
        if (s < cnt) ins10(t, q);
    }
    tau = t[K_ - 1];
    cnt = 0;
}

#define PUSH(q)                                  \
    do {                                         \
        if ((q) < tau) {                         \
            stackm[cnt * 256 + tid] = (q);       \
            ++cnt;                               \
        }                                        \
    } while (0)

// ---------------------------------------------------------------------------
// One 128-candidate chunk: 8 m-subtiles x (K=64 via 2 mfma). A = candidates
// (rows of C), B = this wave's 16 points n (cols of C). C layout (verified):
// col = lane&15 (our n), row = (lane>>4)*4 + reg (candidate).
// Selection: threshold-gated per-lane LDS stack (no wave-coupled insert).
// ---------------------------------------------------------------------------
template <bool SELF>
__device__ __forceinline__ void compute_chunk(const unsigned short* __restrict__ tile,
                                              const float* __restrict__ sn,
                                              const bf16x8 bfrag[2],
                                              float sqn, float (&t)[K_],
                                              float& tau, int& cnt,
                                              float* __restrict__ stackm,
                                              int mg0, int n_my, int c15, int g4,
                                              int tid) {
#pragma unroll
    for (int ms = 0; ms < 8; ++ms) {
        if (__any(cnt > C_ - 4)) compact(t, tau, cnt, stackm, tid);

        const int p_loc = ms * 16 + c15;             // A-fragment row = lane&15
        f32x4 acc = {0.f, 0.f, 0.f, 0.f};
        const int slot0 = (g4) ^ (p_loc & 7);
        const int slot1 = (4 + g4) ^ (p_loc & 7);
        bf16x8 a0 = *(const bf16x8*)(tile + p_loc * 64 + slot0 * 8);
        bf16x8 a1 = *(const bf16x8*)(tile + p_loc * 64 + slot1 * 8);
        acc = __builtin_amdgcn_mfma_f32_16x16x32_bf16(a0, bfrag[0], acc, 0, 0, 0);
        acc = __builtin_amdgcn_mfma_f32_16x16x32_bf16(a1, bfrag[1], acc, 0, 0, 0);

        const f32x4 sq4 = *(const f32x4*)(sn + ms * 16 + g4 * 4);
        float q0 = fmaf(-2.f, acc[0], sqn + sq4[0]);
        float q1 = fmaf(-2.f, acc[1], sqn + sq4[1]);
        float q2 = fmaf(-2.f, acc[2], sqn + sq4[2]);
        float q3 = fmaf(-2.f, acc[3], sqn + sq4[3]);
        if (SELF) {
            const int mg = mg0 + ms * 16 + g4 * 4;   // global candidate id
            if (mg + 0 == n_my) q0 = INF_;
            if (mg + 1 == n_my) q1 = INF_;
            if (mg + 2 == n_my) q2 = INF_;
            if (mg + 3 == n_my) q3 = INF_;
        }
        PUSH(q0);
        PUSH(q1);
        PUSH(q2);
        PUSH(q3);
    }
}

// ---------------------------------------------------------------------------
// Main: grid = B x 128 row-groups x 4 candidate-splits = 1024 blocks
// (4 blocks/CU, 16 waves/CU). Block = 4 waves x 16 rows, 2048 candidates.
// ---------------------------------------------------------------------------
__global__ __launch_bounds__(256, 4) void knn_main_kernel(const uint16_t* __restrict__ Xsw,
                                                          const float* __restrict__ norms,
                                                          float* __restrict__ part) {
    __shared__ __align__(16) unsigned short tile[TILE_M * 64];  // 16 KB (mb alias)
    __shared__ __align__(16) float sn[TILE_M];
    __shared__ __align__(16) float stackm[C_ * 256];            // 16 KB

    const int tid = threadIdx.x;
    const int lane = tid & 63;
    const int wid = tid >> 6;
    const int blk = blockIdx.x;
    const int cs = blk & 3;
    const int rb = (blk >> 2) & 127;
    const int b = blk >> 9;
    const int nbase = rb * ROWS_PB;
    const int cbase = cs * CAND_PB;
    const int c15 = lane & 15;
    const int g4 = lane >> 4;

    // B-fragments: this wave's 16 rows, 2 K-steps, from swizzled global layout
    const int n_my = nbase + wid * 16 + c15;
    bf16x8 bfrag[2];
    {
        const uint16_t* row = Xsw + ((size_t)(b * N_ + n_my)) * 64;
#pragma unroll
        for (int ks = 0; ks < 2; ++ks) {
            const int slot = (ks * 4 + g4) ^ (n_my & 7);
            bfrag[ks] = *(const bf16x8*)(row + slot * 8);
        }
    }
    const float sqn = norms[b * N_ + n_my];

    float t[K_];
#pragma unroll
    for (int j = 0; j < K_; ++j) t[j] = INF_;
    float tau = INF_;
    int cnt = 0;

    // local chunk index containing this block's rows (all 64 rows share it)
    const int selfc = (nbase >> 7) - cs * NCH;   // may be out of [0,NCH)

    // prologue: issue chunk-0 loads
    uint4 stg[4];
    float4 stn;
    {
        const uint4* src = (const uint4*)(Xsw + ((size_t)(b * N_) + cbase) * 64);
#pragma unroll
        for (int i = 0; i < 4; ++i) stg[i] = src[tid + i * 256];
        if (tid < 32) stn = ((const float4*)(norms + b * N_ + cbase))[tid];
    }

    for (int ch = 0; ch < NCH; ++ch) {
        if (ch) __syncthreads();                 // prev compute done
        {
            uint4* dst = (uint4*)tile;
#pragma unroll
            for (int i = 0; i < 4; ++i) dst[tid + i * 256] = stg[i];
            if (tid < 32) ((float4*)sn)[tid] = stn;
        }
        __syncthreads();                         // tile ready
        if (ch + 1 < NCH) {                      // issue next loads early
            const uint4* src = (const uint4*)(Xsw + ((size_t)(b * N_) + cbase +
                                                     (size_t)(ch + 1) * TILE_M) * 64);
#pragma unroll
            for (int i = 0; i < 4; ++i) stg[i] = src[tid + i * 256];
            if (tid < 32)
                stn = ((const float4*)(norms + b * N_ + cbase + (ch + 1) * TILE_M))[tid];
        }
        const int mg0 = cbase + ch * TILE_M;
        if (ch == selfc)
            compute_chunk<true>(tile, sn, bfrag, sqn, t, tau, cnt, stackm,
                                mg0, n_my, c15, g4, tid);
        else
            compute_chunk<false>(tile, sn, bfrag, sqn, t, tau, cnt, stackm,
                                 mg0, n_my, c15, g4, tid);
    }
    compact(t, tau, cnt, stackm, tid);           // drain remaining survivors

    // in-block merge of the 4 g4 partial lists per row (mb aliases tile)
    __syncthreads();
    float* mb = (float*)tile;                    // 256 lists x 10 = 10.24 KB
    {
        float* my = mb + (wid * 64 + lane) * K_;
#pragma unroll
        for (int j = 0; j < K_; ++j) my[j] = t[j];
    }
    __syncthreads();
    if (tid < ROWS_PB) {
        const int w = tid >> 4, c = tid & 15;
        float o[K_];
#pragma unroll
        for (int j = 0; j < K_; ++j) o[j] = INF_;
        for (int g = 0; g < 4; ++g) {
            const float* src = mb + (w * 64 + g * 16 + c) * K_;
#pragma unroll
            for (int j = 0; j < K_; ++j) ins10(o, src[j]);
        }
        float* dst = part + ((size_t)(b * N_ + nbase + tid) * CSPLIT + cs) * K_;
#pragma unroll
        for (int j = 0; j < K_; ++j) dst[j] = o[j];
    }
}

// ---------------------------------------------------------------------------
// Merge CSPLIT partial lists per point, compute S_n, block-reduce.
// S_n = 0.5 * (9*log q9 - sum_{j<9} log qj), q = clamped squared distance.
// ---------------------------------------------------------------------------
__global__ __launch_bounds__(256) void merge_kernel(const float* __restrict__ part,
                                                    float* __restrict__ bsum) {
    __shared__ float red[256];
    const int tid = threadIdx.x;
    const int p = blockIdx.x * 256 + tid;        // 0 .. B*N-1
    const float* src = part + (size_t)p * CSPLIT * K_;

    float t[K_];
#pragma unroll
    for (int j = 0; j < K_; ++j) t[j] = INF_;
    for (int i = 0; i < CSPLIT * K_; ++i) ins10(t, src[i]);

    const float q9 = fmaxf(t[K_ - 1], 1e-12f);
    float S = 9.f * logf(q9);
#pragma unroll
    for (int j = 0; j < K_ - 1; ++j) S -= logf(fmaxf(t[j], 1e-12f));
    S *= 0.5f;

    red[tid] = S;
    __syncthreads();
    for (int off = 128; off > 0; off >>= 1) {
        if (tid < off) red[tid] += red[tid + off];
        __syncthreads();
    }
    if (tid == 0) bsum[blockIdx.x] = red[0];
}

// ---------------------------------------------------------------------------
__global__ void final_kernel(const float* __restrict__ bsum, float* __restrict__ out) {
    if (threadIdx.x == 0) {
        for (int b = 0; b < B_; ++b) {
            float s = 0.f;
            for (int i = 0; i < N_ / 256; ++i) s += bsum[b * (N_ / 256) + i];
            out[b] = 9.f * (float)N_ / s;
        }
    }
}

// ---------------------------------------------------------------------------
extern "C" void kernel_launch(void* const* d_in, const int* in_sizes, int n_in,
                              void* d_out, int out_size, void* d_ws, size_t ws_size,
                              hipStream_t stream) {
    const float* X = (const float*)d_in[0];
    float* out = (float*)d_out;

    // ws: Xsw (2 MB bf16 swizzled) | norms (64 KB) | part (2.62 MB) | bsum
    uint16_t* Xsw = (uint16_t*)d_ws;
    float* norms = (float*)((char*)d_ws + (size_t)B_ * N_ * D_ * sizeof(uint16_t));
    float* part = norms + (size_t)B_ * N_;
    float* bsum = part + (size_t)B_ * N_ * CSPLIT * K_;

    prep_kernel<<<(B_ * N_ * 8) / 256, 256, 0, stream>>>(X, Xsw, norms);
    knn_main_kernel<<<B_ * (N_ / ROWS_PB) * CSPLIT, 256, 0, stream>>>(Xsw, norms, part);
    merge_kernel<<<(B_ * N_) / 256, 256, 0, stream>>>(part, bsum);
    final_kernel<<<1, 64, 0, stream>>>(bsum, out);
}

// Round 4
// 107.845 us; speedup vs baseline: 3.9215x; 1.2362x over previous
//
#include <hip/hip_runtime.h>
#include <math.h>
#include <stdint.h>

#define B_ 2
#define N_ 8192
#define D_ 64
#define K_ 10
#define CSPLIT 8                 // candidate-axis split
#define CAND_PB (N_ / CSPLIT)    // 1024 candidates per block
#define TILE_M 64                // candidates per chunk
#define NCH (CAND_PB / TILE_M)   // 16 chunks
#define ROWS_PB 128              // 4 waves x 32 rows
#define C_ 16                    // per-lane survivor-stack capacity
#define INF_ 3.4e38f

typedef __attribute__((ext_vector_type(8))) short bf16x8;
typedef __attribute__((ext_vector_type(4))) float f32x4;
typedef __attribute__((ext_vector_type(16))) float f32x16;

// Async global->LDS (DMA, no VGPR round-trip). LDS dest = uniform base +
// lane*size (HW); global src is per-lane. AS casts via integer round-trip.
__device__ __forceinline__ void glds16(const void* g, void* l) {
    __builtin_amdgcn_global_load_lds(
        (const __attribute__((address_space(1))) unsigned int*)(uintptr_t)g,
        (__attribute__((address_space(3))) unsigned int*)(uint32_t)(uintptr_t)l,
        16, 0, 0);
}
__device__ __forceinline__ void glds4(const void* g, void* l) {
    __builtin_amdgcn_global_load_lds(
        (const __attribute__((address_space(1))) unsigned int*)(uintptr_t)g,
        (__attribute__((address_space(3))) unsigned int*)(uint32_t)(uintptr_t)l,
        4, 0, 0);
}

// ---------------------------------------------------------------------------
// Prep: f32 -> bf16 (RNE) with XOR slot-swizzle baked into the global layout,
// plus bf16-consistent squared norms. Thread = (point, 8-dim slot).
// Layout: Xsw[point][slot^(point&7)][8 bf16]; row stride 64 halves (128 B).
// ---------------------------------------------------------------------------
__global__ __launch_bounds__(256) void prep_kernel(const float* __restrict__ X,
                                                   uint16_t* __restrict__ Xsw,
                                                   float* __restrict__ norms) {
    const int id = blockIdx.x * 256 + threadIdx.x;   // 0 .. B*N*8-1
    const int p = id >> 3;                           // global point
    const int slot = id & 7;
    const float4* s4 = (const float4*)(X + (size_t)p * D_ + slot * 8);
    float4 va = s4[0], vb = s4[1];
    float v[8] = {va.x, va.y, va.z, va.w, vb.x, vb.y, vb.z, vb.w};
    uint32_t h[8];
    float ss = 0.f;
#pragma unroll
    for (int i = 0; i < 8; ++i) {
        uint32_t u = __float_as_uint(v[i]);
        uint32_t r = (u + 0x7FFFu + ((u >> 16) & 1u)) & 0xFFFF0000u;  // RNE
        h[i] = r >> 16;
        float rv = __uint_as_float(r);
        ss = fmaf(rv, rv, ss);
    }
    uint4 w;
    w.x = h[0] | (h[1] << 16);
    w.y = h[2] | (h[3] << 16);
    w.z = h[4] | (h[5] << 16);
    w.w = h[6] | (h[7] << 16);
    *(uint4*)(Xsw + (size_t)p * D_ + (size_t)((slot ^ (p & 7)) * 8)) = w;
    ss += __shfl_xor(ss, 1);
    ss += __shfl_xor(ss, 2);
    ss += __shfl_xor(ss, 4);
    if (slot == 0) norms[p] = ss;
}

// ---------------------------------------------------------------------------
// Main: grid = B x 64 row-groups x 8 candidate-splits = 1024 blocks
// (4 blocks/CU). Block = 4 waves x 32 rows (32x32x16 MFMA), 1024 candidates.
// Selection in s-domain (maximize s = dot - (|xm|^2+|xn|^2)/2; q = -2s),
// via tau-gated per-lane LDS survivor stack; norms folded into MFMA C-init.
// ---------------------------------------------------------------------------
__global__ __launch_bounds__(256, 4) void knn_main_kernel(const uint16_t* __restrict__ Xsw,
                                                          const float* __restrict__ norms,
                                                          float* __restrict__ part) {
    __shared__ __align__(16) uint16_t tile[2][TILE_M * 64];  // 2 x 8 KB
    __shared__ __align__(16) float sn[2][TILE_M];            // 2 x 256 B
    __shared__ __align__(16) float stackm[C_ * 256];         // 16 KB

    const int tid = threadIdx.x;
    const int lane = tid & 63;
    const int wid = tid >> 6;
    const int hi = lane >> 5;
    const int c31 = lane & 31;
    const int blk = blockIdx.x;
    const int cs = blk & 7;
    const int rb = (blk >> 3) & 63;
    const int b = blk >> 9;
    const int nbase = rb * ROWS_PB;
    const int cbase = cs * CAND_PB;

    // B-fragments: this wave's 32 rows (col = lane&31), 4 K-steps of 16.
    const int n_my = nbase + wid * 32 + c31;
    bf16x8 bfrag[4];
    {
        const uint16_t* row = Xsw + ((size_t)(b * N_ + n_my)) * 64;
#pragma unroll
        for (int j = 0; j < 4; ++j) {
            const int slot = (2 * j + hi) ^ (n_my & 7);
            bfrag[j] = *(const bf16x8*)(row + slot * 8);
        }
    }
    const float h = -0.5f * norms[b * N_ + n_my];

    float t[K_];                     // s-domain top-10, descending; t[9] = tau
#pragma unroll
    for (int j = 0; j < K_; ++j) t[j] = -INF_;
    float tau = -INF_;
    int cnt = 0;

    const uint16_t* gX = Xsw + ((size_t)b * N_ + cbase) * 64;
    const float* gN = norms + b * N_ + cbase;

    auto stage = [&](int buf, int ch) {
        const char* g = (const char*)(gX + (size_t)ch * TILE_M * 64) + wid * 2048 + lane * 16;
        char* l = (char*)&tile[buf][0] + wid * 2048;   // wave-uniform
        glds16(g, l);
        glds16(g + 1024, l + 1024);
        if (wid == 0) glds4(gN + ch * TILE_M + lane, &sn[buf][0]);
    };

    auto compact_fn = [&]() {
#pragma unroll
        for (int s = 0; s < C_; ++s) {
            const float q = stackm[s * 256 + tid];
            if (s < cnt && q > t[K_ - 1]) {
                t[K_ - 1] = q;
#pragma unroll
                for (int j = K_ - 1; j > 0; --j) {
                    const float a = fmaxf(t[j - 1], t[j]);
                    const float bm = fminf(t[j - 1], t[j]);
                    t[j - 1] = a;
                    t[j] = bm;
                }
            }
        }
        tau = t[K_ - 1];
        cnt = 0;
    };

    stage(0, 0);
    __syncthreads();   // compiler drains vmcnt before s_barrier -> tile 0 ready

    for (int ch = 0; ch < NCH; ++ch) {
        const int cur = ch & 1;
        if (ch + 1 < NCH) stage(cur ^ 1, ch + 1);   // async, flies under compute
        const int mg0 = cbase + ch * TILE_M;
        const bool sf = (mg0 < nbase + ROWS_PB) && (mg0 + TILE_M > nbase);
        const uint16_t* tl = &tile[cur][0];
        const float* snb = &sn[cur][0];

#pragma unroll
        for (int ms = 0; ms < 2; ++ms) {
            const int rb32 = ms * 32;
            const int r_my = rb32 + c31;             // A row this lane supplies
            const float* sp = snb + rb32 + 4 * hi;   // broadcast reads
            const f32x4 s0 = *(const f32x4*)(sp);
            const f32x4 s1 = *(const f32x4*)(sp + 8);
            const f32x4 s2 = *(const f32x4*)(sp + 16);
            const f32x4 s3 = *(const f32x4*)(sp + 24);
            f32x16 acc;
#pragma unroll
            for (int e = 0; e < 4; ++e) {            // C-init: -0.5*(sqm+sqn)
                acc[e] = fmaf(-0.5f, s0[e], h);
                acc[4 + e] = fmaf(-0.5f, s1[e], h);
                acc[8 + e] = fmaf(-0.5f, s2[e], h);
                acc[12 + e] = fmaf(-0.5f, s3[e], h);
            }
#pragma unroll
            for (int j = 0; j < 4; ++j) {
                const int slot = (2 * j + hi) ^ (r_my & 7);
                const bf16x8 a = *(const bf16x8*)(tl + r_my * 64 + slot * 8);
                acc = __builtin_amdgcn_mfma_f32_32x32x16_bf16(a, bfrag[j], acc, 0, 0, 0);
            }
            if (sf) {                                 // self-exclusion
#pragma unroll
                for (int r = 0; r < 16; ++r) {
                    const int mg = mg0 + rb32 + (r & 3) + 8 * (r >> 2) + 4 * hi;
                    if (mg == n_my) acc[r] = -INF_;
                }
            }
            if (__any(cnt > C_ - 8)) compact_fn();
#pragma unroll
            for (int r = 0; r < 8; ++r) {
                if (acc[r] > tau) { stackm[cnt * 256 + tid] = acc[r]; ++cnt; }
            }
            if (__any(cnt > C_ - 8)) compact_fn();
#pragma unroll
            for (int r = 8; r < 16; ++r) {
                if (acc[r] > tau) { stackm[cnt * 256 + tid] = acc[r]; ++cnt; }
            }
        }
        __syncthreads();   // drains the async stage issued above + sync
    }
    compact_fn();          // drain remaining survivors

    // in-block merge: 2 half-lane lists per row; dump lists into tile alias
    float* mb = (float*)&tile[0][0];    // 256 * 10 * 4 = 10240 B
    {
        float* my = mb + tid * K_;
#pragma unroll
        for (int j = 0; j < K_; ++j) my[j] = t[j];
    }
    __syncthreads();
    if (tid < 128) {
        const int w = tid >> 5, r = tid & 31;
        const float* la = mb + (w * 64 + r) * K_;
        const float* lb = mb + (w * 64 + 32 + r) * K_;
        float o[K_];
#pragma unroll
        for (int j = 0; j < K_; ++j) o[j] = la[j];
#pragma unroll
        for (int j = 0; j < K_; ++j) {
            const float q = lb[j];
            if (q > o[K_ - 1]) {
                o[K_ - 1] = q;
#pragma unroll
                for (int jj = K_ - 1; jj > 0; --jj) {
                    const float a = fmaxf(o[jj - 1], o[jj]);
                    const float bm = fminf(o[jj - 1], o[jj]);
                    o[jj - 1] = a;
                    o[jj] = bm;
                }
            }
        }
        float* dst = part + ((size_t)(b * N_ + nbase + w * 32 + r) * CSPLIT + cs) * K_;
#pragma unroll
        for (int j = 0; j < K_; ++j) dst[j] = -2.f * o[j];   // back to q = d^2
    }
}

// ---------------------------------------------------------------------------
// Merge CSPLIT partial lists per point, compute S_n, block-reduce.
// S_n = 0.5 * (9*log q9 - sum_{j<9} log qj), q clamped at 1e-12.
// ---------------------------------------------------------------------------
__global__ __launch_bounds__(256) void merge_kernel(const float* __restrict__ part,
                                                    float* __restrict__ bsum) {
    __shared__ float red[256];
    const int tid = threadIdx.x;
    const int p = blockIdx.x * 256 + tid;        // 0 .. B*N-1
    const float* src = part + (size_t)p * CSPLIT * K_;

    float t[K_];
#pragma unroll
    for (int j = 0; j < K_; ++j) t[j] = INF_;
    for (int i = 0; i < CSPLIT * K_; ++i) {
        const float q = src[i];
        if (q < t[K_ - 1]) {
            t[K_ - 1] = q;
#pragma unroll
            for (int j = K_ - 1; j > 0; --j) {
                const float lo = fminf(t[j - 1], t[j]);
                const float hh = fmaxf(t[j - 1], t[j]);
                t[j - 1] = lo;
                t[j] = hh;
            }
        }
    }

    const float q9 = fmaxf(t[K_ - 1], 1e-12f);
    float S = 9.f * logf(q9);
#pragma unroll
    for (int j = 0; j < K_ - 1; ++j) S -= logf(fmaxf(t[j], 1e-12f));
    S *= 0.5f;

    red[tid] = S;
    __syncthreads();
    for (int off = 128; off > 0; off >>= 1) {
        if (tid < off) red[tid] += red[tid + off];
        __syncthreads();
    }
    if (tid == 0) bsum[blockIdx.x] = red[0];
}

// ---------------------------------------------------------------------------
__global__ void final_kernel(const float* __restrict__ bsum, float* __restrict__ out) {
    if (threadIdx.x == 0) {
        for (int b = 0; b < B_; ++b) {
            float s = 0.f;
            for (int i = 0; i < N_ / 256; ++i) s += bsum[b * (N_ / 256) + i];
            out[b] = 9.f * (float)N_ / s;
        }
    }
}

// ---------------------------------------------------------------------------
extern "C" void kernel_launch(void* const* d_in, const int* in_sizes, int n_in,
                              void* d_out, int out_size, void* d_ws, size_t ws_size,
                              hipStream_t stream) {
    const float* X = (const float*)d_in[0];
    float* out = (float*)d_out;

    // ws: Xsw (2 MB bf16 swizzled) | norms (64 KB) | part (5.24 MB) | bsum
    uint16_t* Xsw = (uint16_t*)d_ws;
    float* norms = (float*)((char*)d_ws + (size_t)B_ * N_ * D_ * sizeof(uint16_t));
    float* part = norms + (size_t)B_ * N_;
    float* bsum = part + (size_t)B_ * N_ * CSPLIT * K_;

    prep_kernel<<<(B_ * N_ * 8) / 256, 256, 0, stream>>>(X, Xsw, norms);
    knn_main_kernel<<<B_ * (N_ / ROWS_PB) * CSPLIT, 256, 0, stream>>>(Xsw, norms, part);
    merge_kernel<<<(B_ * N_) / 256, 256, 0, stream>>>(part, bsum);
    final_kernel<<<1, 64, 0, stream>>>(bsum, out);
}

// Round 5
// 96.645 us; speedup vs baseline: 4.3760x; 1.1159x over previous
//
#include <hip/hip_runtime.h>
#include <math.h>
#include <stdint.h>

#define B_ 2
#define N_ 8192
#define D_ 64
#define K_ 10
#define CSPLIT 8                 // candidate-axis split
#define CAND_PB (N_ / CSPLIT)    // 1024 candidates per block
#define TILE_M 64                // candidates per chunk
#define NCH (CAND_PB / TILE_M)   // 16 chunks
#define ROWS_PB 128              // 4 waves x 32 rows
#define C_ 16                    // per-lane survivor-stack capacity
#define INF_ 3.4e38f

typedef __attribute__((ext_vector_type(8))) short bf16x8;
typedef __attribute__((ext_vector_type(4))) float f32x4;
typedef __attribute__((ext_vector_type(16))) float f32x16;

// Async global->LDS DMA. LDS dest = wave-uniform base + lane*16 (HW);
// global src is per-lane.
__device__ __forceinline__ void glds16(const void* g, void* l) {
    __builtin_amdgcn_global_load_lds(
        (const __attribute__((address_space(1))) unsigned int*)(uintptr_t)g,
        (__attribute__((address_space(3))) unsigned int*)(uint32_t)(uintptr_t)l,
        16, 0, 0);
}

__device__ __forceinline__ uint32_t rne_bf16(float f) {
    uint32_t u = __float_as_uint(f);
    return ((u + 0x7FFFu + ((u >> 16) & 1u)) >> 16) & 0xFFFFu;
}

// ---------------------------------------------------------------------------
// Prep: f32 -> bf16 (RNE) with XOR slot-swizzle baked into the global layout;
// norm-extension rows Na (A-side: [-.5sq_hi, -.5sq_lo, 1, 1, 0..]) and
// Nb (B-side: [1, 1, -.5sq_hi, -.5sq_lo, 0..]), 16 halves each.
// Thread = (point, 8-dim slot).
// ---------------------------------------------------------------------------
__global__ __launch_bounds__(256) void prep_kernel(const float* __restrict__ X,
                                                   uint16_t* __restrict__ Xsw,
                                                   uint16_t* __restrict__ Na,
                                                   uint16_t* __restrict__ Nb) {
    const int id = blockIdx.x * 256 + threadIdx.x;   // 0 .. B*N*8-1
    const int p = id >> 3;                           // global point
    const int slot = id & 7;
    const float4* s4 = (const float4*)(X + (size_t)p * D_ + slot * 8);
    float4 va = s4[0], vb = s4[1];
    float v[8] = {va.x, va.y, va.z, va.w, vb.x, vb.y, vb.z, vb.w};
    uint32_t h[8];
    float ss = 0.f;
#pragma unroll
    for (int i = 0; i < 8; ++i) {
        uint32_t u = __float_as_uint(v[i]);
        uint32_t r = (u + 0x7FFFu + ((u >> 16) & 1u)) & 0xFFFF0000u;  // RNE
        h[i] = r >> 16;
        float rv = __uint_as_float(r);
        ss = fmaf(rv, rv, ss);
    }
    uint4 w;
    w.x = h[0] | (h[1] << 16);
    w.y = h[2] | (h[3] << 16);
    w.z = h[4] | (h[5] << 16);
    w.w = h[6] | (h[7] << 16);
    *(uint4*)(Xsw + (size_t)p * D_ + (size_t)((slot ^ (p & 7)) * 8)) = w;
    ss += __shfl_xor(ss, 1);
    ss += __shfl_xor(ss, 2);
    ss += __shfl_xor(ss, 4);

    // two-term bf16 split of -0.5*|x|^2 (error ~2^-18 relative)
    const float hv = -0.5f * ss;
    const uint32_t bh = rne_bf16(hv);
    const float rem = hv - __uint_as_float(bh << 16);
    const uint32_t bl = rne_bf16(rem);
    const uint32_t packn = bh | (bl << 16);
    const uint32_t ONE2 = 0x3F803F80u;
    const uint4 z4 = {0, 0, 0, 0};
    if (slot == 0) {
        uint4 a = {packn, ONE2, 0, 0};
        *(uint4*)(Na + (size_t)p * 16) = a;
    } else if (slot == 1) {
        *(uint4*)(Na + (size_t)p * 16 + 8) = z4;
    } else if (slot == 2) {
        uint4 bvec = {ONE2, packn, 0, 0};
        *(uint4*)(Nb + (size_t)p * 16) = bvec;
    } else if (slot == 3) {
        *(uint4*)(Nb + (size_t)p * 16 + 8) = z4;
    }
}

// ---------------------------------------------------------------------------
// Main: grid = B x 64 row-groups x 8 candidate-splits = 1024 blocks
// (4 blocks/CU). Block = 4 waves x 32 rows (32x32x16 MFMA), 1024 candidates.
// s = dot - .5|xm|^2 - .5|xn|^2 computed ENTIRELY by MFMA (5th K-step carries
// the norm terms). Selection: tau-gated per-lane LDS stack; compaction =
// bitonic sort16 + bitonic merge into register top-10 (straight-line min/max).
// ---------------------------------------------------------------------------
__global__ __launch_bounds__(256, 4) void knn_main_kernel(const uint16_t* __restrict__ Xsw,
                                                          const uint16_t* __restrict__ Na,
                                                          const uint16_t* __restrict__ Nb,
                                                          float* __restrict__ part) {
    __shared__ __align__(16) uint16_t tile[2][TILE_M * 64];  // 2 x 8 KB
    __shared__ __align__(16) uint16_t ext[2][TILE_M * 16];   // 2 x 2 KB
    __shared__ __align__(16) float stackm[C_ * 256];         // 16 KB

    const int tid = threadIdx.x;
    const int lane = tid & 63;
    const int wid = tid >> 6;
    const int hi = lane >> 5;
    const int c31 = lane & 31;
    const int blk = blockIdx.x;
    const int cs = blk & 7;
    const int rb = (blk >> 3) & 63;
    const int b = blk >> 9;
    const int nbase = rb * ROWS_PB;
    const int cbase = cs * CAND_PB;

    // B-fragments: this wave's 32 rows (col = lane&31), 4 K-steps of 16,
    // plus the norm-extension fragment from Nb.
    const int n_my = nbase + wid * 32 + c31;
    bf16x8 bfrag[4], bext;
    {
        const uint16_t* row = Xsw + ((size_t)(b * N_ + n_my)) * 64;
#pragma unroll
        for (int j = 0; j < 4; ++j) {
            const int slot = (2 * j + hi) ^ (n_my & 7);
            bfrag[j] = *(const bf16x8*)(row + slot * 8);
        }
        bext = *(const bf16x8*)(Nb + (size_t)(b * N_ + n_my) * 16 + hi * 8);
    }

    f32x16 zro;
#pragma unroll
    for (int i = 0; i < 16; ++i) zro[i] = 0.f;

    float t[K_];                     // s-domain top-10, descending
#pragma unroll
    for (int j = 0; j < K_; ++j) t[j] = -INF_;
    float tau = -INF_;
    int cnt = 0;

    const uint16_t* gX = Xsw + ((size_t)b * N_ + cbase) * 64;
    const uint16_t* gA = Na + ((size_t)b * N_ + cbase) * 16;

    auto stage = [&](int buf, int ch) {
        const char* g = (const char*)(gX + (size_t)ch * TILE_M * 64) + wid * 2048 + lane * 16;
        char* l = (char*)&tile[buf][0] + wid * 2048;   // wave-uniform base
        glds16(g, l);
        glds16(g + 1024, l + 1024);
        if (wid == 3) {  // 2 KB ext tile
            const char* ge = (const char*)(gA + (size_t)ch * TILE_M * 16) + lane * 16;
            char* le = (char*)&ext[buf][0];
            glds16(ge, le);
            glds16(ge + 1024, le + 1024);
        }
    };

    // compaction: bitonic sort16 of stack (desc) + bitonic merge with t[10]
    auto compact_fn = [&]() {
        float v[16];
#pragma unroll
        for (int s = 0; s < C_; ++s) {
            const float q = stackm[s * 256 + tid];
            v[s] = (s < cnt) ? q : -INF_;
        }
        // bitonic sort, descending
#pragma unroll
        for (int k = 2; k <= 16; k <<= 1) {
#pragma unroll
            for (int j = k >> 1; j > 0; j >>= 1) {
#pragma unroll
                for (int i = 0; i < 16; ++i) {
                    const int ixj = i ^ j;
                    if (ixj > i) {
                        const float a = v[i], c = v[ixj];
                        const float mx = fmaxf(a, c), mn = fminf(a, c);
                        const bool up = ((i & k) == 0);
                        v[i] = up ? mx : mn;
                        v[ixj] = up ? mn : mx;
                    }
                }
            }
        }
        // merge: L[i] = max(tpad[i], v[15-i]) is bitonic; clean descending
        float L[16];
#pragma unroll
        for (int i = 0; i < 16; ++i) {
            const float ti = (i < K_) ? t[i] : -INF_;
            L[i] = fmaxf(ti, v[15 - i]);
        }
#pragma unroll
        for (int j = 8; j > 0; j >>= 1) {
#pragma unroll
            for (int i = 0; i < 16; ++i) {
                const int ixj = i ^ j;
                if (ixj > i) {
                    const float a = L[i], c = L[ixj];
                    L[i] = fmaxf(a, c);
                    L[ixj] = fminf(a, c);
                }
            }
        }
#pragma unroll
        for (int i = 0; i < K_; ++i) t[i] = L[i];
        tau = t[K_ - 1];
        cnt = 0;
    };

    stage(0, 0);
    __syncthreads();   // vmcnt drained before s_barrier -> tile 0 ready

    for (int ch = 0; ch < NCH; ++ch) {
        const int cur = ch & 1;
        if (ch + 1 < NCH) stage(cur ^ 1, ch + 1);   // flies under compute
        const int mg0 = cbase + ch * TILE_M;
        const bool sf = (mg0 < nbase + ROWS_PB) && (mg0 + TILE_M > nbase);
        const uint16_t* tl = &tile[cur][0];
        const uint16_t* el = &ext[cur][0];

#pragma unroll
        for (int ms = 0; ms < 2; ++ms) {
            const int rb32 = ms * 32;
            const int r_my = rb32 + c31;             // A row this lane supplies
            const bf16x8 ae = *(const bf16x8*)(el + r_my * 16 + hi * 8);
            f32x16 acc = __builtin_amdgcn_mfma_f32_32x32x16_bf16(ae, bext, zro, 0, 0, 0);
#pragma unroll
            for (int j = 0; j < 4; ++j) {
                const int slot = (2 * j + hi) ^ (r_my & 7);
                const bf16x8 a = *(const bf16x8*)(tl + r_my * 64 + slot * 8);
                acc = __builtin_amdgcn_mfma_f32_32x32x16_bf16(a, bfrag[j], acc, 0, 0, 0);
            }
            if (sf) {                                 // self-exclusion
#pragma unroll
                for (int r = 0; r < 16; ++r) {
                    const int mg = mg0 + rb32 + (r & 3) + 8 * (r >> 2) + 4 * hi;
                    if (mg == n_my) acc[r] = -INF_;
                }
            }
            if (__any(cnt > 8)) compact_fn();
#pragma unroll
            for (int r = 0; r < 8; ++r) {
                if (acc[r] > tau) { stackm[cnt * 256 + tid] = acc[r]; ++cnt; }
            }
            if (__any(cnt > 8)) compact_fn();
#pragma unroll
            for (int r = 8; r < 16; ++r) {
                if (acc[r] > tau) { stackm[cnt * 256 + tid] = acc[r]; ++cnt; }
            }
        }
        __syncthreads();   // drains async stage + sync
    }
    compact_fn();          // final drain -> t[0..9] descending

    // in-block merge of the 2 hi-lane lists per row (stride-11 to avoid
    // bank conflicts: gcd(11,32)=1 -> 2-way, free)
    __syncthreads();
    float* mb = (float*)&tile[0][0];    // 256 lists x 11 floats = 11264 B
    {
        float* my = mb + tid * 11;
#pragma unroll
        for (int j = 0; j < K_; ++j) my[j] = t[j];
    }
    __syncthreads();
    if (tid < 128) {
        const int w = tid >> 5, r = tid & 31;
        const float* la = mb + (w * 64 + r) * 11;
        const float* lb = mb + (w * 64 + 32 + r) * 11;
        float o[K_];
#pragma unroll
        for (int j = 0; j < K_; ++j) o[j] = la[j];
#pragma unroll
        for (int j = 0; j < K_; ++j) {
            const float q = lb[j];
            if (q > o[K_ - 1]) {
                o[K_ - 1] = q;
#pragma unroll
                for (int jj = K_ - 1; jj > 0; --jj) {
                    const float a = fmaxf(o[jj - 1], o[jj]);
                    const float bm = fminf(o[jj - 1], o[jj]);
                    o[jj - 1] = a;
                    o[jj] = bm;
                }
            }
        }
        float* dst = part + ((size_t)(b * N_ + nbase + w * 32 + r) * CSPLIT + cs) * K_;
#pragma unroll
        for (int j = 0; j < K_; ++j) dst[j] = -2.f * o[j];   // back to q = d^2
    }
}

// ---------------------------------------------------------------------------
// Merge CSPLIT partial lists per point, compute S_n, block-reduce.
// S_n = 0.5 * (9*log q9 - sum_{j<9} log qj), q clamped at 1e-12.
// ---------------------------------------------------------------------------
__global__ __launch_bounds__(256) void merge_kernel(const float* __restrict__ part,
                                                    float* __restrict__ bsum) {
    __shared__ float red[256];
    const int tid = threadIdx.x;
    const int p = blockIdx.x * 256 + tid;        // 0 .. B*N-1
    const float* src = part + (size_t)p * CSPLIT * K_;

    float t[K_];
#pragma unroll
    for (int j = 0; j < K_; ++j) t[j] = INF_;
    for (int i = 0; i < CSPLIT * K_; ++i) {
        const float q = src[i];
        if (q < t[K_ - 1]) {
            t[K_ - 1] = q;
#pragma unroll
            for (int j = K_ - 1; j > 0; --j) {
                const float lo = fminf(t[j - 1], t[j]);
                const float hh = fmaxf(t[j - 1], t[j]);
                t[j - 1] = lo;
                t[j] = hh;
            }
        }
    }

    const float q9 = fmaxf(t[K_ - 1], 1e-12f);
    float S = 9.f * logf(q9);
#pragma unroll
    for (int j = 0; j < K_ - 1; ++j) S -= logf(fmaxf(t[j], 1e-12f));
    S *= 0.5f;

    red[tid] = S;
    __syncthreads();
    for (int off = 128; off > 0; off >>= 1) {
        if (tid < off) red[tid] += red[tid + off];
        __syncthreads();
    }
    if (tid == 0) bsum[blockIdx.x] = red[0];
}

// ---------------------------------------------------------------------------
__global__ void final_kernel(const float* __restrict__ bsum, float* __restrict__ out) {
    if (threadIdx.x == 0) {
        for (int b = 0; b < B_; ++b) {
            float s = 0.f;
            for (int i = 0; i < N_ / 256; ++i) s += bsum[b * (N_ / 256) + i];
            out[b] = 9.f * (float)N_ / s;
        }
    }
}

// ---------------------------------------------------------------------------
extern "C" void kernel_launch(void* const* d_in, const int* in_sizes, int n_in,
                              void* d_out, int out_size, void* d_ws, size_t ws_size,
                              hipStream_t stream) {
    const float* X = (const float*)d_in[0];
    float* out = (float*)d_out;

    // ws: Xsw (2 MB) | Na (512 KB) | Nb (512 KB) | part (5.24 MB) | bsum
    uint16_t* Xsw = (uint16_t*)d_ws;
    uint16_t* Na = Xsw + (size_t)B_ * N_ * D_;
    uint16_t* Nb = Na + (size_t)B_ * N_ * 16;
    float* part = (float*)(Nb + (size_t)B_ * N_ * 16);
    float* bsum = part + (size_t)B_ * N_ * CSPLIT * K_;

    prep_kernel<<<(B_ * N_ * 8) / 256, 256, 0, stream>>>(X, Xsw, Na, Nb);
    knn_main_kernel<<<B_ * (N_ / ROWS_PB) * CSPLIT, 256, 0, stream>>>(Xsw, Na, Nb, part);
    merge_kernel<<<(B_ * N_) / 256, 256, 0, stream>>>(part, bsum);
    final_kernel<<<1, 64, 0, stream>>>(bsum, out);
}

// Round 6
// 88.860 us; speedup vs baseline: 4.7594x; 1.0876x over previous
//
#include <hip/hip_runtime.h>
#include <math.h>
#include <stdint.h>

#define B_ 2
#define N_ 8192
#define D_ 64
#define K_ 10
#define CSPLIT 8                 // candidate-axis split
#define CAND_PB (N_ / CSPLIT)    // 1024 candidates per block
#define TILE_M 64                // candidates per chunk
#define NCH (CAND_PB / TILE_M)   // 16 chunks
#define ROWS_PB 128              // 4 waves x 32 rows
#define C_ 16                    // per-lane survivor-stack capacity
#define INF_ 3.4e38f

typedef __attribute__((ext_vector_type(8))) short bf16x8;
typedef __attribute__((ext_vector_type(4))) float f32x4;
typedef __attribute__((ext_vector_type(16))) float f32x16;

// Async global->LDS DMA. LDS dest = wave-uniform base + lane*16 (HW);
// global src is per-lane.
__device__ __forceinline__ void glds16(const void* g, void* l) {
    __builtin_amdgcn_global_load_lds(
        (const __attribute__((address_space(1))) unsigned int*)(uintptr_t)g,
        (__attribute__((address_space(3))) unsigned int*)(uint32_t)(uintptr_t)l,
        16, 0, 0);
}

__device__ __forceinline__ uint32_t rne_bf16(float f) {
    uint32_t u = __float_as_uint(f);
    return ((u + 0x7FFFu + ((u >> 16) & 1u)) >> 16) & 0xFFFFu;
}

// ---------------------------------------------------------------------------
// Prep: f32 -> bf16 (RNE) with XOR slot-swizzle baked into the global layout;
// norm-extension rows Na (A-side: [-.5sq_hi, -.5sq_lo, 1, 1, 0..]) and
// Nb (B-side: [1, 1, -.5sq_hi, -.5sq_lo, 0..]), 16 halves each.
// Thread = (point, 8-dim slot).
// ---------------------------------------------------------------------------
__global__ __launch_bounds__(256) void prep_kernel(const float* __restrict__ X,
                                                   uint16_t* __restrict__ Xsw,
                                                   uint16_t* __restrict__ Na,
                                                   uint16_t* __restrict__ Nb) {
    const int id = blockIdx.x * 256 + threadIdx.x;   // 0 .. B*N*8-1
    const int p = id >> 3;                           // global point
    const int slot = id & 7;
    const float4* s4 = (const float4*)(X + (size_t)p * D_ + slot * 8);
    float4 va = s4[0], vb = s4[1];
    float v[8] = {va.x, va.y, va.z, va.w, vb.x, vb.y, vb.z, vb.w};
    uint32_t h[8];
    float ss = 0.f;
#pragma unroll
    for (int i = 0; i < 8; ++i) {
        uint32_t u = __float_as_uint(v[i]);
        uint32_t r = (u + 0x7FFFu + ((u >> 16) & 1u)) & 0xFFFF0000u;  // RNE
        h[i] = r >> 16;
        float rv = __uint_as_float(r);
        ss = fmaf(rv, rv, ss);
    }
    uint4 w;
    w.x = h[0] | (h[1] << 16);
    w.y = h[2] | (h[3] << 16);
    w.z = h[4] | (h[5] << 16);
    w.w = h[6] | (h[7] << 16);
    *(uint4*)(Xsw + (size_t)p * D_ + (size_t)((slot ^ (p & 7)) * 8)) = w;
    ss += __shfl_xor(ss, 1);
    ss += __shfl_xor(ss, 2);
    ss += __shfl_xor(ss, 4);

    // two-term bf16 split of -0.5*|x|^2 (error ~2^-18 relative)
    const float hv = -0.5f * ss;
    const uint32_t bh = rne_bf16(hv);
    const float rem = hv - __uint_as_float(bh << 16);
    const uint32_t bl = rne_bf16(rem);
    const uint32_t packn = bh | (bl << 16);
    const uint32_t ONE2 = 0x3F803F80u;
    const uint4 z4 = {0, 0, 0, 0};
    if (slot == 0) {
        uint4 a = {packn, ONE2, 0, 0};
        *(uint4*)(Na + (size_t)p * 16) = a;
    } else if (slot == 1) {
        *(uint4*)(Na + (size_t)p * 16 + 8) = z4;
    } else if (slot == 2) {
        uint4 bvec = {ONE2, packn, 0, 0};
        *(uint4*)(Nb + (size_t)p * 16) = bvec;
    } else if (slot == 3) {
        *(uint4*)(Nb + (size_t)p * 16 + 8) = z4;
    }
}

// ---------------------------------------------------------------------------
// Main: grid = B x 64 row-groups x 8 candidate-splits = 1024 blocks
// (4 blocks/CU). Block = 4 waves x 32 rows (32x32x16 MFMA), 1024 candidates.
// s = dot - .5|xm|^2 - .5|xn|^2 computed ENTIRELY by MFMA (5th K-step carries
// the norm terms). Selection: tau-gated per-lane LDS stack with BRANCHLESS
// push (always-store, conditionally advance slot); compaction = bitonic
// sort16 + bitonic merge into register top-10 (straight-line min/max).
// ---------------------------------------------------------------------------
__global__ __launch_bounds__(256, 4) void knn_main_kernel(const uint16_t* __restrict__ Xsw,
                                                          const uint16_t* __restrict__ Na,
                                                          const uint16_t* __restrict__ Nb,
                                                          float* __restrict__ part) {
    __shared__ __align__(16) uint16_t tile[2][TILE_M * 64];  // 2 x 8 KB
    __shared__ __align__(16) uint16_t ext[2][TILE_M * 16];   // 2 x 2 KB
    __shared__ __align__(16) float stackm[C_ * 256];         // 16 KB

    const int tid = threadIdx.x;
    const int lane = tid & 63;
    const int wid = tid >> 6;
    const int hi = lane >> 5;
    const int c31 = lane & 31;
    const int blk = blockIdx.x;
    const int cs = blk & 7;
    const int rb = (blk >> 3) & 63;
    const int b = blk >> 9;
    const int nbase = rb * ROWS_PB;
    const int cbase = cs * CAND_PB;

    // B-fragments: this wave's 32 rows (col = lane&31), 4 K-steps of 16,
    // plus the norm-extension fragment from Nb.
    const int n_my = nbase + wid * 32 + c31;
    bf16x8 bfrag[4], bext;
    {
        const uint16_t* row = Xsw + ((size_t)(b * N_ + n_my)) * 64;
#pragma unroll
        for (int j = 0; j < 4; ++j) {
            const int slot = (2 * j + hi) ^ (n_my & 7);
            bfrag[j] = *(const bf16x8*)(row + slot * 8);
        }
        bext = *(const bf16x8*)(Nb + (size_t)(b * N_ + n_my) * 16 + hi * 8);
    }

    f32x16 zro;
#pragma unroll
    for (int i = 0; i < 16; ++i) zro[i] = 0.f;

    float t[K_];                     // s-domain top-10, descending
#pragma unroll
    for (int j = 0; j < K_; ++j) t[j] = -INF_;
    float tau = -INF_;
    int so = tid;                    // stack slot cursor; cnt = so >> 8

    const uint16_t* gX = Xsw + ((size_t)b * N_ + cbase) * 64;
    const uint16_t* gA = Na + ((size_t)b * N_ + cbase) * 16;

    auto stage = [&](int buf, int ch) {
        const char* g = (const char*)(gX + (size_t)ch * TILE_M * 64) + wid * 2048 + lane * 16;
        char* l = (char*)&tile[buf][0] + wid * 2048;   // wave-uniform base
        glds16(g, l);
        glds16(g + 1024, l + 1024);
        if (wid == 3) {  // 2 KB ext tile
            const char* ge = (const char*)(gA + (size_t)ch * TILE_M * 16) + lane * 16;
            char* le = (char*)&ext[buf][0];
            glds16(ge, le);
            glds16(ge + 1024, le + 1024);
        }
    };

    // compaction: bitonic sort16 of stack (desc) + bitonic merge with t[10]
    auto compact_fn = [&]() {
        const int cnt = so >> 8;
        float v[16];
#pragma unroll
        for (int s = 0; s < C_; ++s) {
            const float q = stackm[s * 256 + tid];
            v[s] = (s < cnt) ? q : -INF_;
        }
        // bitonic sort, descending
#pragma unroll
        for (int k = 2; k <= 16; k <<= 1) {
#pragma unroll
            for (int j = k >> 1; j > 0; j >>= 1) {
#pragma unroll
                for (int i = 0; i < 16; ++i) {
                    const int ixj = i ^ j;
                    if (ixj > i) {
                        const float a = v[i], c = v[ixj];
                        const float mx = fmaxf(a, c), mn = fminf(a, c);
                        const bool up = ((i & k) == 0);
                        v[i] = up ? mx : mn;
                        v[ixj] = up ? mn : mx;
                    }
                }
            }
        }
        // merge: L[i] = max(tpad[i], v[15-i]) is bitonic; clean descending
        float L[16];
#pragma unroll
        for (int i = 0; i < 16; ++i) {
            const float ti = (i < K_) ? t[i] : -INF_;
            L[i] = fmaxf(ti, v[15 - i]);
        }
#pragma unroll
        for (int j = 8; j > 0; j >>= 1) {
#pragma unroll
            for (int i = 0; i < 16; ++i) {
                const int ixj = i ^ j;
                if (ixj > i) {
                    const float a = L[i], c = L[ixj];
                    L[i] = fmaxf(a, c);
                    L[ixj] = fminf(a, c);
                }
            }
        }
#pragma unroll
        for (int i = 0; i < K_; ++i) t[i] = L[i];
        tau = t[K_ - 1];
        so = tid;
    };

    stage(0, 0);
    __syncthreads();   // vmcnt drained before s_barrier -> tile 0 ready

    for (int ch = 0; ch < NCH; ++ch) {
        const int cur = ch & 1;
        if (ch + 1 < NCH) stage(cur ^ 1, ch + 1);   // flies under compute
        const int mg0 = cbase + ch * TILE_M;
        const bool sf = (mg0 < nbase + ROWS_PB) && (mg0 + TILE_M > nbase);
        const uint16_t* tl = &tile[cur][0];
        const uint16_t* el = &ext[cur][0];

#pragma unroll
        for (int ms = 0; ms < 2; ++ms) {
            const int rb32 = ms * 32;
            const int r_my = rb32 + c31;             // A row this lane supplies
            const bf16x8 ae = *(const bf16x8*)(el + r_my * 16 + hi * 8);
            f32x16 acc = __builtin_amdgcn_mfma_f32_32x32x16_bf16(ae, bext, zro, 0, 0, 0);
#pragma unroll
            for (int j = 0; j < 4; ++j) {
                const int slot = (2 * j + hi) ^ (r_my & 7);
                const bf16x8 a = *(const bf16x8*)(tl + r_my * 64 + slot * 8);
                acc = __builtin_amdgcn_mfma_f32_32x32x16_bf16(a, bfrag[j], acc, 0, 0, 0);
            }
            if (sf) {                                 // self-exclusion
#pragma unroll
                for (int r = 0; r < 16; ++r) {
                    const int mg = mg0 + rb32 + (r & 3) + 8 * (r >> 2) + 4 * hi;
                    if (mg == n_my) acc[r] = -INF_;
                }
            }
            // branchless pushes; gate every 4 (need 4 free slots)
#pragma unroll
            for (int r0 = 0; r0 < 16; r0 += 4) {
                if (__any((so >> 8) > C_ - 4)) compact_fn();
#pragma unroll
                for (int r = r0; r < r0 + 4; ++r) {
                    const float q = acc[r];
                    stackm[so] = q;
                    so += (q > tau) ? 256 : 0;
                }
            }
        }
        __syncthreads();   // drains async stage + sync
    }
    compact_fn();          // final drain -> t[0..9] descending

    // in-block merge of the 2 hi-lane lists per row (stride-11: gcd(11,32)=1)
    __syncthreads();
    float* mb = (float*)&tile[0][0];    // 256 lists x 11 floats = 11264 B
    {
        float* my = mb + tid * 11;
#pragma unroll
        for (int j = 0; j < K_; ++j) my[j] = t[j];
    }
    __syncthreads();
    if (tid < 128) {
        const int w = tid >> 5, r = tid & 31;
        const float* la = mb + (w * 64 + r) * 11;
        const float* lb = mb + (w * 64 + 32 + r) * 11;
        float o[K_];
#pragma unroll
        for (int j = 0; j < K_; ++j) o[j] = la[j];
#pragma unroll
        for (int j = 0; j < K_; ++j) {
            const float q = lb[j];
            if (q > o[K_ - 1]) {
                o[K_ - 1] = q;
#pragma unroll
                for (int jj = K_ - 1; jj > 0; --jj) {
                    const float a = fmaxf(o[jj - 1], o[jj]);
                    const float bm = fminf(o[jj - 1], o[jj]);
                    o[jj - 1] = a;
                    o[jj] = bm;
                }
            }
        }
        float* dst = part + ((size_t)(b * N_ + nbase + w * 32 + r) * CSPLIT + cs) * K_;
#pragma unroll
        for (int j = 0; j < K_; ++j) dst[j] = -2.f * o[j];   // back to q = d^2
    }
}

// ---------------------------------------------------------------------------
// Merge CSPLIT partial lists per point, compute S_n, block-reduce.
// S_n = 0.5 * (9*log q9 - sum_{j<9} log qj), q clamped at 1e-12.
// ---------------------------------------------------------------------------
__global__ __launch_bounds__(256) void merge_kernel(const float* __restrict__ part,
                                                    float* __restrict__ bsum) {
    __shared__ float red[256];
    const int tid = threadIdx.x;
    const int p = blockIdx.x * 256 + tid;        // 0 .. B*N-1
    const float* src = part + (size_t)p * CSPLIT * K_;

    float t[K_];
#pragma unroll
    for (int j = 0; j < K_; ++j) t[j] = INF_;
    for (int i = 0; i < CSPLIT * K_; ++i) {
        const float q = src[i];
        if (q < t[K_ - 1]) {
            t[K_ - 1] = q;
#pragma unroll
            for (int j = K_ - 1; j > 0; --j) {
                const float lo = fminf(t[j - 1], t[j]);
                const float hh = fmaxf(t[j - 1], t[j]);
                t[j - 1] = lo;
                t[j] = hh;
            }
        }
    }

    const float q9 = fmaxf(t[K_ - 1], 1e-12f);
    float S = 9.f * logf(q9);
#pragma unroll
    for (int j = 0; j < K_ - 1; ++j) S -= logf(fmaxf(t[j], 1e-12f));
    S *= 0.5f;

    red[tid] = S;
    __syncthreads();
    for (int off = 128; off > 0; off >>= 1) {
        if (tid < off) red[tid] += red[tid + off];
        __syncthreads();
    }
    if (tid == 0) bsum[blockIdx.x] = red[0];
}

// ---------------------------------------------------------------------------
__global__ void final_kernel(const float* __restrict__ bsum, float* __restrict__ out) {
    if (threadIdx.x == 0) {
        for (int b = 0; b < B_; ++b) {
            float s = 0.f;
            for (int i = 0; i < N_ / 256; ++i) s += bsum[b * (N_ / 256) + i];
            out[b] = 9.f * (float)N_ / s;
        }
    }
}

// ---------------------------------------------------------------------------
extern "C" void kernel_launch(void* const* d_in, const int* in_sizes, int n_in,
                              void* d_out, int out_size, void* d_ws, size_t ws_size,
                              hipStream_t stream) {
    const float* X = (const float*)d_in[0];
    float* out = (float*)d_out;

    // ws: Xsw (2 MB) | Na (512 KB) | Nb (512 KB) | part (5.24 MB) | bsum
    uint16_t* Xsw = (uint16_t*)d_ws;
    uint16_t* Na = Xsw + (size_t)B_ * N_ * D_;
    uint16_t* Nb = Na + (size_t)B_ * N_ * 16;
    float* part = (float*)(Nb + (size_t)B_ * N_ * 16);
    float* bsum = part + (size_t)B_ * N_ * CSPLIT * K_;

    prep_kernel<<<(B_ * N_ * 8) / 256, 256, 0, stream>>>(X, Xsw, Na, Nb);
    knn_main_kernel<<<B_ * (N_ / ROWS_PB) * CSPLIT, 256, 0, stream>>>(Xsw, Na, Nb, part);
    merge_kernel<<<(B_ * N_) / 256, 256, 0, stream>>>(part, bsum);
    final_kernel<<<1, 64, 0, stream>>>(bsum, out);
}